// Round 4
// baseline (757.985 us; speedup 1.0000x reference)
//
#include <hip/hip_runtime.h>
#include <hip/hip_bf16.h>

#define NN 102400      // B*T*NODES
#define DD 64
#define EE 1638400
#define L1C 96
#define L2C 64
#define TT 32
#define NODESC 400
#define BB 8
#define SS 3200        // B*NODES
#define G4 256         // 4*D

// ---------------- workspace layout (floats) ----------------
// big block [0, 26,214,400): a1 | g1 | ent(csr), later overwritten by xg
#define OFF_A1   ((size_t)6553600)    // NN*64
#define OFF_G1   ((size_t)13107200)   // NN*96 -> ends 22,937,600
#define OFF_ENT  ((size_t)22937600)   // EE int2 (2*EE floats) -> ends 26,214,400
#define OFF_XG   ((size_t)0)          // NN*256
#define OFF_H2   ((size_t)26214400)   // NN*64
#define OFF_G2   ((size_t)32768000)   // NN*64
#define OFF_DIS  ((size_t)39321600)   // NN
#define OFF_ROFF ((size_t)39424000)   // NN+1 ints (padded)
#define OFF_CUR  ((size_t)39526416)   // NN ints
#define OFF_HL   ((size_t)39628816)   // SS*64
#define OFF_ST   ((size_t)39833616)   // 256   -> total 39,833,872 floats = 159.3 MB

__device__ __forceinline__ void fma4(float4& a, float s, const float4& w) {
    a.x = fmaf(s, w.x, a.x); a.y = fmaf(s, w.y, a.y);
    a.z = fmaf(s, w.z, a.z); a.w = fmaf(s, w.w, a.w);
}
__device__ __forceinline__ float rcp_f(float x) { return __builtin_amdgcn_rcpf(x); }
__device__ __forceinline__ float sigm_f(float x) {
    x = fminf(fmaxf(x, -30.f), 30.f);
    return rcp_f(1.f + __expf(-x));
}
__device__ __forceinline__ float tanh_f(float x) {
    x = fminf(fmaxf(x, -15.f), 15.f);
    float e = __expf(2.f * x);
    return (e - 1.f) * rcp_f(e + 1.f);
}

// ---------------- init: zero cursor (hist) + stats ----------------
__global__ void init_zero(int* cursor, float* st) {
    int idx = blockIdx.x * 256 + threadIdx.x;
    if (idx < NN) cursor[idx] = 0;
    if (blockIdx.x == 0 && threadIdx.x < 128) st[threadIdx.x] = 0.f;
}

// ---------------- normalization stats ----------------
__global__ __launch_bounds__(256) void col_sums(const float* __restrict__ x, float* __restrict__ st) {
    int c = threadIdx.x & 63;
    size_t i = (size_t)blockIdx.x * 256 + threadIdx.x;
    size_t stride = (size_t)gridDim.x * 256;
    float s = 0.f, q = 0.f;
    for (size_t e = i; e < (size_t)NN * 64; e += stride) {
        float v = x[e]; s += v; q = fmaf(v, v, q);
    }
    __shared__ float ls[128];
    if (threadIdx.x < 128) ls[threadIdx.x] = 0.f;
    __syncthreads();
    atomicAdd(&ls[c], s); atomicAdd(&ls[64 + c], q);
    __syncthreads();
    if (threadIdx.x < 128) atomicAdd(&st[threadIdx.x], ls[threadIdx.x]);
}

__global__ void finalize_stats(float* st) {
    int c = threadIdx.x;
    if (c < 64) {
        float s = st[c], q = st[64 + c];
        float mean = s / (float)NN;
        float var = (q - s * s / (float)NN) / (float)(NN - 1);
        st[128 + c] = mean;
        st[192 + c] = rsqrtf(fmaxf(var, 1e-20f));
    }
}

// ---------------- CSR build (dest-sorted, packed 8B entries) ----------------
__global__ void hist_acc(const int* __restrict__ ei, int* __restrict__ cnt) {
    int e = blockIdx.x * 256 + threadIdx.x;
    atomicAdd(&cnt[ei[EE + e]], 1);
}

// single-block exclusive scan over NN counts; writes roff[0..NN] and cursor[0..NN-1]
__global__ __launch_bounds__(1024) void scan_kernel(int* __restrict__ cnt, int* __restrict__ roff, int* __restrict__ cursor) {
    __shared__ int part[1024];
    int tid = threadIdx.x;
    int base = tid * (NN / 1024);
    int s = 0;
    for (int i = 0; i < NN / 1024; ++i) s += cnt[base + i];
    part[tid] = s;
    __syncthreads();
    for (int d = 1; d < 1024; d <<= 1) {
        int v = (tid >= d) ? part[tid - d] : 0;
        __syncthreads();
        part[tid] += v;
        __syncthreads();
    }
    int run = part[tid] - s;     // exclusive prefix of this thread's range
    for (int i = 0; i < NN / 1024; ++i) {
        int c = cnt[base + i];
        roff[base + i] = run;
        cursor[base + i] = run;
        run += c;
    }
    if (tid == 1023) roff[NN] = run;
}

__global__ void csr_fill(const int* __restrict__ ei, const float* __restrict__ ea,
                         int* __restrict__ cursor, int2* __restrict__ ent) {
    int e = blockIdx.x * 256 + threadIdx.x;
    int d = ei[EE + e];
    int pos = atomicAdd(&cursor[d], 1);
    ent[pos] = make_int2(ei[e], __float_as_int(fabsf(ea[2 * (size_t)e])));
}

// deg[n] = 1 + sum of raw weights in row n (self-loop weight 1); dis = rsqrt(deg)
__global__ void row_norm(const int* __restrict__ roff, const int2* __restrict__ ent, float* __restrict__ dis) {
    int n = blockIdx.x * 256 + threadIdx.x;
    int e0 = roff[n], e1 = roff[n + 1];
    float deg = 1.f;
    for (int e = e0; e < e1; ++e) deg += __int_as_float(ent[e].y);
    dis[n] = rsqrtf(deg);
}

// ---------------- tiled f32 GEMM ----------------
template<int K, int NC, int MB, int THREADS, bool PRELU, bool TRANSW, bool XGOUT>
__global__ __launch_bounds__(THREADS) void gemm_tiled(
    const float* __restrict__ A, const float* __restrict__ Wm,
    const float* __restrict__ bin, const float* __restrict__ bo1, const float* __restrict__ bo2,
    float* __restrict__ Cm, int ldC)
{
    __shared__ float As[MB * K];
    __shared__ float Ws[K * NC];
    const int cb0 = TRANSW ? ((int)blockIdx.y * NC) : 0;   // xg column-half select

    if (!TRANSW) {
        for (int i = threadIdx.x; i < K * NC / 4; i += THREADS)
            ((float4*)Ws)[i] = ((const float4*)Wm)[i];
    } else {
        for (int i = threadIdx.x; i < NC * (K / 4); i += THREADS) {
            int g = i / (K / 4); int d = (i % (K / 4)) * 4;
            float4 v = *(const float4*)(Wm + (size_t)(cb0 + g) * K + d);
            Ws[(d + 0) * NC + g] = v.x; Ws[(d + 1) * NC + g] = v.y;
            Ws[(d + 2) * NC + g] = v.z; Ws[(d + 3) * NC + g] = v.w;
        }
    }
    size_t row0 = (size_t)blockIdx.x * MB;
    for (int i = threadIdx.x; i < MB * (K / 4); i += THREADS) {
        int r = i / (K / 4); int c = (i % (K / 4)) * 4;
        float4 a = *(const float4*)(A + (row0 + r) * K + c);
        if (PRELU) {
            a.x = fmaxf(a.x + bin[c + 0], 0.f); a.y = fmaxf(a.y + bin[c + 1], 0.f);
            a.z = fmaxf(a.z + bin[c + 2], 0.f); a.w = fmaxf(a.w + bin[c + 3], 0.f);
        }
        ((float4*)As)[i] = a;
    }
    __syncthreads();

    constexpr int NCT = NC / 4;
    int tc = threadIdx.x % NCT;
    int tr = threadIdx.x / NCT;
    int r = tr * 4;
    float4 acc[4];
    acc[0] = acc[1] = acc[2] = acc[3] = make_float4(0.f, 0.f, 0.f, 0.f);

    #pragma unroll 8
    for (int d4 = 0; d4 < K / 4; ++d4) {
        float4 w0 = ((const float4*)Ws)[(4 * d4 + 0) * NCT + tc];
        float4 w1 = ((const float4*)Ws)[(4 * d4 + 1) * NCT + tc];
        float4 w2 = ((const float4*)Ws)[(4 * d4 + 2) * NCT + tc];
        float4 w3 = ((const float4*)Ws)[(4 * d4 + 3) * NCT + tc];
        #pragma unroll
        for (int i = 0; i < 4; ++i) {
            float4 av = ((const float4*)As)[(r + i) * (K / 4) + d4];
            fma4(acc[i], av.x, w0); fma4(acc[i], av.y, w1);
            fma4(acc[i], av.z, w2); fma4(acc[i], av.w, w3);
        }
    }

    if (!XGOUT) {
        #pragma unroll
        for (int i = 0; i < 4; ++i) {
            size_t row = row0 + r + i;
            *(float4*)(Cm + row * ldC + tc * 4) = acc[i];
        }
    } else {
        int cb = cb0 + tc * 4;
        float4 bs;
        bs.x = bo1[cb + 0] + bo2[cb + 0]; bs.y = bo1[cb + 1] + bo2[cb + 1];
        bs.z = bo1[cb + 2] + bo2[cb + 2]; bs.w = bo1[cb + 3] + bo2[cb + 3];
        #pragma unroll
        for (int i = 0; i < 4; ++i) {
            int n = (int)row0 + r + i;                      // n = b*T*NODES + t*NODES + node
            int b_ = n / (TT * NODESC);
            int rem = n - b_ * (TT * NODESC);
            int t = rem / NODESC;
            int node = rem - t * NODESC;
            int orow = (b_ * NODESC + node) * TT + t;       // seq-major, time inner
            float4 o = acc[i];
            o.x += bs.x; o.y += bs.y; o.z += bs.z; o.w += bs.w;
            *(float4*)(Cm + (size_t)orow * ldC + cb) = o;
        }
    }
}

// ---------------- GCN aggregation: gather over packed CSR, dis folded in ----------------
// g[n] = dis[n] * ( dis[n]*h[n] + sum_e w_e*dis[src_e]*h[src_e] )
// NORM variant normalizes h rows on the fly from raw x + column stats (saves xn round-trip).
template<int C4, bool NORM>
__global__ __launch_bounds__(256) void gcn_gather(const float* __restrict__ h, const int* __restrict__ roff,
                                                  const int2* __restrict__ ent, const float* __restrict__ dis,
                                                  const float* __restrict__ st, float* __restrict__ g) {
    unsigned int idx = blockIdx.x * 256 + threadIdx.x;
    unsigned int n = idx / C4, q = idx % C4;
    float4 mean4, istd4;
    if (NORM) {
        mean4 = ((const float4*)(st + 128))[q];
        istd4 = ((const float4*)(st + 192))[q];
    }
    float dn = dis[n];
    float4 acc = ((const float4*)h)[(size_t)n * C4 + q];
    if (NORM) {
        acc.x = (acc.x - mean4.x) * istd4.x; acc.y = (acc.y - mean4.y) * istd4.y;
        acc.z = (acc.z - mean4.z) * istd4.z; acc.w = (acc.w - mean4.w) * istd4.w;
    }
    acc.x *= dn; acc.y *= dn; acc.z *= dn; acc.w *= dn;
    int e0 = roff[n], e1 = roff[n + 1];
    for (int e = e0; e < e1; ++e) {
        int2 en = ent[e];
        float w = __int_as_float(en.y) * dis[en.x];
        float4 v = ((const float4*)h)[(size_t)en.x * C4 + q];
        if (NORM) {
            v.x = (v.x - mean4.x) * istd4.x; v.y = (v.y - mean4.y) * istd4.y;
            v.z = (v.z - mean4.z) * istd4.z; v.w = (v.w - mean4.w) * istd4.w;
        }
        fma4(acc, w, v);
    }
    acc.x *= dn; acc.y *= dn; acc.z *= dn; acc.w *= dn;
    ((float4*)g)[(size_t)n * C4 + q] = acc;
}

// ---------------- LSTM (recurrent part; xg precomputed) ----------------
// block = 256 threads = 4 waves, 4 seqs/block; thread `tid` owns gate-row `tid`
// (w_hh row in 16 NAMED float4 registers — __launch_bounds__(256,1) lifts the
// VGPR cap that made the compiler spill the weight array in the previous rev).
#define STEPK(i, wv) { float4 hv = hq[i]; \
    acc.x = fmaf(hv.x, wv.x, acc.x); acc.y = fmaf(hv.y, wv.y, acc.y); \
    acc.z = fmaf(hv.z, wv.z, acc.z); acc.w = fmaf(hv.w, wv.w, acc.w); }
#define DOTQ(qq, xv) { const float4* hq = (const float4*)hs[qq]; \
    float4 acc = make_float4(0.f, 0.f, 0.f, 0.f); \
    STEPK(0,r0) STEPK(1,r1) STEPK(2,r2) STEPK(3,r3) STEPK(4,r4) STEPK(5,r5) STEPK(6,r6) STEPK(7,r7) \
    STEPK(8,r8) STEPK(9,r9) STEPK(10,r10) STEPK(11,r11) STEPK(12,r12) STEPK(13,r13) STEPK(14,r14) STEPK(15,r15) \
    gp[qq][tid] = (xv) + (acc.x + acc.y) + (acc.z + acc.w); }

__global__ __launch_bounds__(256, 1) void lstm_kernel(const float* __restrict__ xg, const float* __restrict__ whh,
                                                      float* __restrict__ hlast) {
    __shared__ float hs[4][64];
    __shared__ float gp[4][256];
    const int tid = threadIdx.x;
    const int w = tid >> 6, j = tid & 63;
    const float4* wr = (const float4*)(whh + (size_t)tid * 64);
    const float4 r0 = wr[0],  r1 = wr[1],  r2 = wr[2],  r3 = wr[3];
    const float4 r4 = wr[4],  r5 = wr[5],  r6 = wr[6],  r7 = wr[7];
    const float4 r8 = wr[8],  r9 = wr[9],  r10 = wr[10], r11 = wr[11];
    const float4 r12 = wr[12], r13 = wr[13], r14 = wr[14], r15 = wr[15];
    float c_reg = 0.f, hn = 0.f;
    hs[w][j] = 0.f;
    const float* xb = xg + (size_t)blockIdx.x * 4 * TT * G4 + tid;
    __syncthreads();
    for (int t = 0; t < TT; ++t) {
        float xv0 = xb[(0 * TT + t) * G4];
        float xv1 = xb[(1 * TT + t) * G4];
        float xv2 = xb[(2 * TT + t) * G4];
        float xv3 = xb[(3 * TT + t) * G4];
        DOTQ(0, xv0) DOTQ(1, xv1) DOTQ(2, xv2) DOTQ(3, xv3)
        __syncthreads();                       // gp ready; all hs reads of this step done
        float gi = gp[w][j], gf = gp[w][64 + j], gg = gp[w][128 + j], go = gp[w][192 + j];
        c_reg = sigm_f(gf) * c_reg + sigm_f(gi) * tanh_f(gg);
        hn = sigm_f(go) * tanh_f(c_reg);
        hs[w][j] = hn;
        __syncthreads();                       // hs ready for next step
    }
    hlast[((size_t)blockIdx.x * 4 + w) * 64 + j] = hn;
}

// ---------------- FC head + softmax ----------------
__global__ __launch_bounds__(128) void head_kernel(const float* __restrict__ hl,
                                                   const float* __restrict__ w1, const float* __restrict__ b1,
                                                   const float* __restrict__ w2, const float* __restrict__ b2,
                                                   float* __restrict__ out) {
    __shared__ float hrow[64];
    __shared__ float a1[128];
    __shared__ float lg[3];
    int s = blockIdx.x, tid = threadIdx.x;
    if (tid < 64) hrow[tid] = hl[(size_t)s * 64 + tid];
    __syncthreads();
    {
        const float4* wr = (const float4*)(w1 + (size_t)tid * 64);
        const float4* hq = (const float4*)hrow;
        float4 acc = make_float4(0.f, 0.f, 0.f, 0.f);
        #pragma unroll
        for (int k = 0; k < 16; ++k) {
            float4 wv = wr[k]; float4 hv = hq[k];
            acc.x = fmaf(wv.x, hv.x, acc.x); acc.y = fmaf(wv.y, hv.y, acc.y);
            acc.z = fmaf(wv.z, hv.z, acc.z); acc.w = fmaf(wv.w, hv.w, acc.w);
        }
        a1[tid] = fmaxf((acc.x + acc.y) + (acc.z + acc.w) + b1[tid], 0.f);
    }
    __syncthreads();
    if (tid < 3) {
        const float4* wr = (const float4*)(w2 + (size_t)tid * 128);
        const float4* aq = (const float4*)a1;
        float4 acc = make_float4(0.f, 0.f, 0.f, 0.f);
        #pragma unroll
        for (int k = 0; k < 32; ++k) {
            float4 wv = wr[k]; float4 av = aq[k];
            acc.x = fmaf(wv.x, av.x, acc.x); acc.y = fmaf(wv.y, av.y, acc.y);
            acc.z = fmaf(wv.z, av.z, acc.z); acc.w = fmaf(wv.w, av.w, acc.w);
        }
        lg[tid] = (acc.x + acc.y) + (acc.z + acc.w) + b2[tid];
    }
    __syncthreads();
    if (tid == 0) {
        float m = fmaxf(lg[0], fmaxf(lg[1], lg[2]));
        float e0 = __expf(lg[0] - m), e1 = __expf(lg[1] - m), e2 = __expf(lg[2] - m);
        float inv = 1.f / (e0 + e1 + e2);
        out[(size_t)s * 3 + 0] = e0 * inv;
        out[(size_t)s * 3 + 1] = e1 * inv;
        out[(size_t)s * 3 + 2] = e2 * inv;
    }
}

extern "C" void kernel_launch(void* const* d_in, const int* in_sizes, int n_in,
                              void* d_out, int out_size, void* d_ws, size_t ws_size,
                              hipStream_t stream) {
    (void)in_sizes; (void)n_in; (void)out_size; (void)ws_size;
    const float* x        = (const float*)d_in[0];
    const float* ea       = (const float*)d_in[1];
    const float* conv1_w  = (const float*)d_in[2];
    const float* conv1_b  = (const float*)d_in[3];
    const float* conv2_w  = (const float*)d_in[4];
    const float* conv2_b  = (const float*)d_in[5];
    const float* w_ih     = (const float*)d_in[6];
    const float* w_hh     = (const float*)d_in[7];
    const float* b_ih     = (const float*)d_in[8];
    const float* b_hh     = (const float*)d_in[9];
    const float* fc1_w    = (const float*)d_in[10];
    const float* fc1_b    = (const float*)d_in[11];
    const float* fc2_w    = (const float*)d_in[12];
    const float* fc2_b    = (const float*)d_in[13];
    const int*   ei       = (const int*)d_in[14];
    float* out = (float*)d_out;

    float* W   = (float*)d_ws;
    float* a1  = W + OFF_A1;
    float* g1  = W + OFF_G1;
    float* xg  = W + OFF_XG;
    float* h2  = W + OFF_H2;
    float* g2  = W + OFF_G2;
    float* dis = W + OFF_DIS;
    float* hl  = W + OFF_HL;
    float* st  = W + OFF_ST;
    int*   roff    = (int*)(W + OFF_ROFF);
    int*   cursor  = (int*)(W + OFF_CUR);
    int2*  ent     = (int2*)(W + OFF_ENT);

    // init + normalization stats (normalization itself fused into gather-1)
    init_zero<<<NN / 256, 256, 0, stream>>>(cursor, st);
    col_sums<<<1024, 256, 0, stream>>>(x, st);
    finalize_stats<<<1, 64, 0, stream>>>(st);

    // CSR build (dest-sorted, packed); raw |ea| weights
    hist_acc<<<EE / 256, 256, 0, stream>>>(ei, cursor);
    scan_kernel<<<1, 1024, 0, stream>>>(cursor, roff, cursor);
    csr_fill<<<EE / 256, 256, 0, stream>>>(ei, ea, cursor, ent);
    row_norm<<<NN / 256, 256, 0, stream>>>(roff, ent, dis);

    // GCN layer 1, commuted: a1 = S·normalize(x) (64 cols), then g1 = a1 @ W1 (96 cols)
    gcn_gather<16, true><<<NN * 16 / 256, 256, 0, stream>>>(x, roff, ent, dis, st, a1);
    gemm_tiled<64, 96, 32, 192, false, false, false><<<NN / 32, 192, 0, stream>>>(
        a1, conv1_w, nullptr, nullptr, nullptr, g1, 96);

    // GCN layer 2: h2 = relu(g1+b1) @ W2 (64 cols), then g2 = S·h2
    gemm_tiled<96, 64, 64, 256, true, false, false><<<NN / 64, 256, 0, stream>>>(
        g1, conv2_w, conv1_b, nullptr, nullptr, h2, 64);
    gcn_gather<16, false><<<NN * 16 / 256, 256, 0, stream>>>(h2, roff, ent, dis, nullptr, g2);

    // LSTM input transform: xg = relu(g2+b2) @ w_ih^T + b_ih + b_hh (both col-halves in one launch)
    gemm_tiled<64, 128, 32, 256, true, true, true><<<dim3(NN / 32, 2), 256, 0, stream>>>(
        g2, w_ih, conv2_b, b_ih, b_hh, xg, 256);

    // LSTM recurrence
    lstm_kernel<<<SS / 4, 256, 0, stream>>>(xg, w_hh, hl);

    // FC head + softmax
    head_kernel<<<SS, 128, 0, stream>>>(hl, fc1_w, fc1_b, fc2_w, fc2_b, out);
}